// Round 2
// baseline (295.690 us; speedup 1.0000x reference)
//
#include <hip/hip_runtime.h>

#define NN 4096      // nodes
#define IND 512      // input dim
#define HD 512       // H*D
#define NH 4         // heads
#define DH 128       // per-head dim
#define K3 1536      // split-K for support GEMM

typedef __attribute__((ext_vector_type(8))) short bf16x8;
typedef __attribute__((ext_vector_type(4))) float f32x4;
typedef __attribute__((ext_vector_type(4))) unsigned short us4;
typedef __attribute__((ext_vector_type(8))) unsigned short us8;

__device__ __forceinline__ unsigned short f2bf(float x) {
  union { float f; unsigned u; } a; a.f = x;
  unsigned r = a.u + 0x7FFFu + ((a.u >> 16) & 1u);
  return (unsigned short)(r >> 16);
}
__device__ __forceinline__ float bf2f(unsigned short b) {
  union { float f; unsigned u; } a; a.u = ((unsigned)b) << 16;
  return a.f;
}

// ---------------- prep: inputs -> A3 = [Ah | Ah | Al] (bf16, [4096][1536]) ----
__global__ __launch_bounds__(256) void prep_inputs(const float* __restrict__ x,
                                                   unsigned short* __restrict__ A3) {
  int idx = blockIdx.x * 256 + threadIdx.x;       // 0..2M-1
  int n = idx >> 9, c = idx & 511;
  float v = x[idx];
  unsigned short hi = f2bf(v);
  unsigned short lo = f2bf(v - bf2f(hi));
  size_t base = (size_t)n * K3;
  A3[base + c] = hi;
  A3[base + 512 + c] = hi;
  A3[base + 1024 + c] = lo;
}

// ---------------- prep: weights -> B3T [512 c][1536 k] = [Wh;Wl;Wh]^T, PhT ----
__global__ __launch_bounds__(256) void prep_weights(const float* __restrict__ w,
                                                    const float* __restrict__ pw,
                                                    unsigned short* __restrict__ B3T,
                                                    unsigned short* __restrict__ PhT) {
  int idx = blockIdx.x * 256 + threadIdx.x;       // 0..262143
  int c = idx >> 9, k = idx & 511;
  float v = w[(size_t)k * HD + c];                // strided read (small, L2-absorbed)
  unsigned short hi = f2bf(v);
  unsigned short lo = f2bf(v - bf2f(hi));
  size_t base = (size_t)c * K3;
  B3T[base + k] = hi;
  B3T[base + 512 + k] = lo;
  B3T[base + 1024 + k] = hi;
  float p = pw[(size_t)k * HD + c];
  PhT[(size_t)c * IND + k] = f2bf(p);
}

// ---------------- GEMM: z=0 support (K=1536, split-bf16), z=1 resid (K=512) --
__global__ __launch_bounds__(256) void gemm_kernel(
    const unsigned short* __restrict__ A3, const unsigned short* __restrict__ B3T,
    const unsigned short* __restrict__ PhT,
    float* __restrict__ support, unsigned short* __restrict__ ST,
    float* __restrict__ resid,
    const float* __restrict__ projb, const float* __restrict__ bias) {
  const int z = blockIdx.z;
  const unsigned short* Bp = z ? PhT : B3T;
  const int ldb = z ? IND : K3;
  const int K = z ? IND : K3;
  const int m0 = blockIdx.x * 128;
  const int n0 = blockIdx.y * 128;
  const int tid = threadIdx.x;
  const int lane = tid & 63;
  const int wv = tid >> 6;
  const int wm = wv & 1, wn = wv >> 1;

  __shared__ unsigned short As[128 * 32];
  __shared__ unsigned short Bs[128 * 32];

  f32x4 acc[4][4];
#pragma unroll
  for (int a = 0; a < 4; ++a)
#pragma unroll
    for (int b = 0; b < 4; ++b) acc[a][b] = (f32x4){0.f, 0.f, 0.f, 0.f};

  us8 ra[2], rb[2];
  // preload k0 = 0
#pragma unroll
  for (int s = 0; s < 2; ++s) {
    int idx = tid + s * 256;
    int r = idx >> 2, c = idx & 3;
    ra[s] = *(const us8*)(A3 + (size_t)(m0 + r) * K3 + c * 8);
    rb[s] = *(const us8*)(Bp + (size_t)(n0 + r) * ldb + c * 8);
  }

  const int lrow = lane & 15;
  const int lkb = (lane >> 4) * 8;

  for (int k0 = 0; k0 < K; k0 += 32) {
    __syncthreads();
#pragma unroll
    for (int s = 0; s < 2; ++s) {
      int idx = tid + s * 256;
      *(us8*)(As + idx * 8) = ra[s];
      *(us8*)(Bs + idx * 8) = rb[s];
    }
    __syncthreads();
    int kn = k0 + 32;
    if (kn < K) {
#pragma unroll
      for (int s = 0; s < 2; ++s) {
        int idx = tid + s * 256;
        int r = idx >> 2, c = idx & 3;
        ra[s] = *(const us8*)(A3 + (size_t)(m0 + r) * K3 + kn + c * 8);
        rb[s] = *(const us8*)(Bp + (size_t)(n0 + r) * ldb + kn + c * 8);
      }
    }
    bf16x8 af[4], bfr[4];
#pragma unroll
    for (int mf = 0; mf < 4; ++mf)
      af[mf] = *(const bf16x8*)(As + (wm * 64 + mf * 16 + lrow) * 32 + lkb);
#pragma unroll
    for (int nf = 0; nf < 4; ++nf)
      bfr[nf] = *(const bf16x8*)(Bs + (wn * 64 + nf * 16 + lrow) * 32 + lkb);
#pragma unroll
    for (int mf = 0; mf < 4; ++mf)
#pragma unroll
      for (int nf = 0; nf < 4; ++nf)
        acc[mf][nf] = __builtin_amdgcn_mfma_f32_16x16x32_bf16(af[mf], bfr[nf], acc[mf][nf], 0, 0, 0);
  }

  const int lrow4 = (lane >> 4) * 4;
  const int lcol = lane & 15;
  if (z == 0) {
#pragma unroll
    for (int mf = 0; mf < 4; ++mf) {
#pragma unroll
      for (int nf = 0; nf < 4; ++nf) {
        int rg = m0 + wm * 64 + mf * 16 + lrow4;
        int cg = n0 + wn * 64 + nf * 16 + lcol;
#pragma unroll
        for (int q = 0; q < 4; ++q)
          support[(size_t)(rg + q) * HD + cg] = acc[mf][nf][q];
        us4 st4;
#pragma unroll
        for (int q = 0; q < 4; ++q) st4[q] = f2bf(acc[mf][nf][q]);
        *(us4*)(ST + (size_t)cg * NN + rg) = st4;
      }
    }
  } else {
#pragma unroll
    for (int mf = 0; mf < 4; ++mf) {
#pragma unroll
      for (int nf = 0; nf < 4; ++nf) {
        int rg = m0 + wm * 64 + mf * 16 + lrow4;
        int cg = n0 + wn * 64 + nf * 16 + lcol;
        float addv = projb[cg] + bias[cg];
#pragma unroll
        for (int q = 0; q < 4; ++q)
          resid[(size_t)(rg + q) * HD + cg] = acc[mf][nf][q] + addv;
      }
    }
  }
}

// ---------------- f1/f2 (scaled by log2 e) ----------------------------------
__global__ __launch_bounds__(256) void f1f2_kernel(const float* __restrict__ support,
                                                   const float* __restrict__ wu,
                                                   const float* __restrict__ wv,
                                                   float* __restrict__ g1,
                                                   float* __restrict__ g2) {
  int lane = threadIdx.x & 63;
  int n = blockIdx.x * 4 + (threadIdx.x >> 6);
  const float* srow = support + (size_t)n * HD + lane * 8;
  int h = lane >> 4;
  int d0 = (lane * 8) & 127;
  const float* u = wu + h * DH + d0;
  const float* v = wv + h * DH + d0;
  float du = 0.f, dv = 0.f;
#pragma unroll
  for (int e = 0; e < 8; ++e) {
    float s = srow[e];
    du += s * u[e];
    dv += s * v[e];
  }
#pragma unroll
  for (int off = 1; off < 16; off <<= 1) {
    du += __shfl_xor(du, off);
    dv += __shfl_xor(dv, off);
  }
  if ((lane & 15) == 0) {
    const float L2E = 1.4426950408889634f;
    g1[h * NN + n] = du * L2E;
    g2[h * NN + n] = dv * L2E;
  }
}

// ---------------- max over edges + adjacency bitmask -------------------------
__global__ __launch_bounds__(256) void maxmask_kernel(const float* __restrict__ adj,
                                                      const float* __restrict__ g1,
                                                      const float* __restrict__ g2,
                                                      unsigned long long* __restrict__ bm,
                                                      float* __restrict__ mm) {
  int i = blockIdx.x;
  int tid = threadIdx.x, lane = tid & 63, wv = tid >> 6;
  const float* arow = adj + (size_t)i * NN;
  float m0 = -3.0e38f, m1 = -3.0e38f, m2 = -3.0e38f, m3 = -3.0e38f;
#pragma unroll 4
  for (int it = 0; it < 16; ++it) {
    int j = it * 256 + tid;
    float a = arow[j];
    bool e = (a != 0.0f);
    unsigned long long b = __ballot(e);
    if (lane == 0) bm[(size_t)i * 64 + it * 4 + wv] = b;
    m0 = fmaxf(m0, e ? g1[0 * NN + j] : -3.0e38f);
    m1 = fmaxf(m1, e ? g1[1 * NN + j] : -3.0e38f);
    m2 = fmaxf(m2, e ? g1[2 * NN + j] : -3.0e38f);
    m3 = fmaxf(m3, e ? g1[3 * NN + j] : -3.0e38f);
  }
#pragma unroll
  for (int off = 1; off < 64; off <<= 1) {
    m0 = fmaxf(m0, __shfl_xor(m0, off));
    m1 = fmaxf(m1, __shfl_xor(m1, off));
    m2 = fmaxf(m2, __shfl_xor(m2, off));
    m3 = fmaxf(m3, __shfl_xor(m3, off));
  }
  __shared__ float red[4][4];
  if (lane == 0) {
    red[0][wv] = m0; red[1][wv] = m1; red[2][wv] = m2; red[3][wv] = m3;
  }
  __syncthreads();
  if (tid < 4) {
    int h = tid;
    float gm = fmaxf(fmaxf(red[h][0], red[h][1]), fmaxf(red[h][2], red[h][3]));
    float t = gm + g2[h * NN + i];
    float v = fmaxf(t, 0.2f * t);
    if (gm < -1.0e37f) v = 0.0f;   // no-edge row guard
    mm[h * NN + i] = v;
  }
}

// ---------------- fused masked softmax + PV + residual -----------------------
__global__ __launch_bounds__(256) void attn_kernel(
    const unsigned short* __restrict__ ST,        // [512 d][4096 j] bf16
    const unsigned long long* __restrict__ bm,    // [4096 i][64 words]
    const float* __restrict__ g1, const float* __restrict__ g2,
    const float* __restrict__ mm, const float* __restrict__ resid,
    float* __restrict__ out) {
  int blk = blockIdx.x;                            // rows blk*16 .. +15
  int tid = threadIdx.x;
  int lane = tid & 63;
  int h = tid >> 6;                                // one wave per head

  __shared__ unsigned long long bml[16 * 64];      // 8KB bitmask slice
  {
    const unsigned long long* src = bm + (size_t)blk * (16 * 64);
#pragma unroll
    for (int s = 0; s < 4; ++s) bml[tid + s * 256] = src[tid + s * 256];
  }
  __syncthreads();

  const int il = lane & 15;                        // row (A) / col (B,D)
  const int kg = lane >> 4;                        // k-group
  const int ig = blk * 16 + il;
  const float g2v = g2[h * NN + ig];
  const float mmv = mm[h * NN + ig];
  const unsigned char* bmb = ((const unsigned char*)bml) + il * 512 + kg;
  const float* g1h = g1 + h * NN;
  const unsigned short* stb = ST + (size_t)(h * DH + il) * NN + kg * 8;

  bf16x8 ones;
#pragma unroll
  for (int e = 0; e < 8; ++e) ones[e] = (short)0x3F80;

  f32x4 acc[8];
#pragma unroll
  for (int d = 0; d < 8; ++d) acc[d] = (f32x4){0.f, 0.f, 0.f, 0.f};
  f32x4 asum = (f32x4){0.f, 0.f, 0.f, 0.f};

  union F8 { f32x4 v[2]; float f[8]; };
  F8 gc, gn;
  bf16x8 bc[8], bn[8];

  gc.v[0] = *(const f32x4*)(g1h + kg * 8);
  gc.v[1] = *(const f32x4*)(g1h + kg * 8 + 4);
#pragma unroll
  for (int d = 0; d < 8; ++d)
    bc[d] = *(const bf16x8*)(stb + (size_t)d * 16 * NN);

  for (int jt = 0; jt < NN; jt += 32) {
    int jn = jt + 32;
    if (jn < NN) {
      gn.v[0] = *(const f32x4*)(g1h + jn + kg * 8);
      gn.v[1] = *(const f32x4*)(g1h + jn + kg * 8 + 4);
#pragma unroll
      for (int d = 0; d < 8; ++d)
        bn[d] = *(const bf16x8*)(stb + (size_t)d * 16 * NN + jn);
    }
    unsigned mbyte = bmb[jt >> 3];
    float pv[8];
#pragma unroll
    for (int e = 0; e < 8; ++e) {
      float t = gc.f[e] + g2v;
      float zz = ((mbyte >> e) & 1u) ? t : -1.0e30f;
      // exp2(lrelu(t) - m) = exp2(max(t - m, 0.2t - m)); masked -> underflow to 0
      pv[e] = __builtin_amdgcn_exp2f(fmaxf(zz - mmv, __builtin_fmaf(0.2f, zz, -mmv)));
    }
    union { unsigned u[4]; bf16x8 v; } af;
#pragma unroll
    for (int e2 = 0; e2 < 4; ++e2)
      af.u[e2] = (unsigned)f2bf(pv[2 * e2]) | ((unsigned)f2bf(pv[2 * e2 + 1]) << 16);

#pragma unroll
    for (int d = 0; d < 8; ++d)
      acc[d] = __builtin_amdgcn_mfma_f32_16x16x32_bf16(af.v, bc[d], acc[d], 0, 0, 0);
    asum = __builtin_amdgcn_mfma_f32_16x16x32_bf16(af.v, ones, asum, 0, 0, 0);

    if (jn < NN) {
      gc.v[0] = gn.v[0]; gc.v[1] = gn.v[1];
#pragma unroll
      for (int d = 0; d < 8; ++d) bc[d] = bn[d];
    }
  }

  float rs[4];
#pragma unroll
  for (int q = 0; q < 4; ++q) rs[q] = asum[q] > 0.0f ? 1.0f / asum[q] : 0.0f;
#pragma unroll
  for (int d = 0; d < 8; ++d) {
    int cg = h * DH + d * 16 + il;
#pragma unroll
    for (int q = 0; q < 4; ++q) {
      int rg = blk * 16 + kg * 4 + q;
      out[(size_t)rg * HD + cg] = acc[d][q] * rs[q] + resid[(size_t)rg * HD + cg];
    }
  }
}

// ---------------- launcher ---------------------------------------------------
extern "C" void kernel_launch(void* const* d_in, const int* in_sizes, int n_in,
                              void* d_out, int out_size, void* d_ws, size_t ws_size,
                              hipStream_t stream) {
  const float* inputs = (const float*)d_in[0];
  const float* adj = (const float*)d_in[1];
  const float* weight = (const float*)d_in[2];
  const float* wu = (const float*)d_in[3];
  const float* wv = (const float*)d_in[4];
  const float* bias = (const float*)d_in[5];
  const float* projw = (const float*)d_in[6];
  const float* projb = (const float*)d_in[7];
  float* out = (float*)d_out;

  char* ws = (char*)d_ws;
  size_t off = 0;
  unsigned short* A3 = (unsigned short*)(ws + off); off += (size_t)NN * K3 * 2;          // 12.58MB
  unsigned short* B3T = (unsigned short*)(ws + off); off += (size_t)HD * K3 * 2;         // 1.57MB
  unsigned short* PhT = (unsigned short*)(ws + off); off += (size_t)HD * IND * 2;        // 0.52MB
  float* support = (float*)(ws + off); off += (size_t)NN * HD * 4;                       // 8MB
  unsigned short* ST = (unsigned short*)(ws + off); off += (size_t)HD * NN * 2;          // 4MB
  float* resid = (float*)(ws + off); off += (size_t)NN * HD * 4;                         // 8MB
  float* g1 = (float*)(ws + off); off += (size_t)NH * NN * 4;
  float* g2 = (float*)(ws + off); off += (size_t)NH * NN * 4;
  float* mm = (float*)(ws + off); off += (size_t)NH * NN * 4;
  unsigned long long* bm = (unsigned long long*)(ws + off); off += (size_t)NN * 64 * 8;  // 2MB

  prep_inputs<<<(NN * IND) / 256, 256, 0, stream>>>(inputs, A3);
  prep_weights<<<(IND * HD) / 256, 256, 0, stream>>>(weight, projw, B3T, PhT);
  gemm_kernel<<<dim3(32, 4, 2), 256, 0, stream>>>(A3, B3T, PhT, support, ST, resid, projb, bias);
  f1f2_kernel<<<NN / 4, 256, 0, stream>>>(support, wu, wv, g1, g2);
  maxmask_kernel<<<NN, 256, 0, stream>>>(adj, g1, g2, bm, mm);
  attn_kernel<<<NN / 16, 256, 0, stream>>>(ST, bm, g1, g2, mm, resid, out);
}

// Round 3
// 219.981 us; speedup vs baseline: 1.3442x; 1.3442x over previous
//
#include <hip/hip_runtime.h>

#define NN 4096      // nodes
#define IND 512      // input dim
#define HD 512       // H*D
#define NH 4         // heads
#define DH 128       // per-head dim
#define K3 1536      // split-K for support GEMM

typedef __attribute__((ext_vector_type(8))) short bf16x8;
typedef __attribute__((ext_vector_type(4))) float f32x4;
typedef __attribute__((ext_vector_type(4))) unsigned short us4;
typedef __attribute__((ext_vector_type(8))) unsigned short us8;

typedef __attribute__((address_space(3))) void lds_void;
typedef const __attribute__((address_space(1))) void glob_void;

__device__ __forceinline__ void gll16(const void* g, void* l) {
  __builtin_amdgcn_global_load_lds((glob_void*)g, (lds_void*)l, 16, 0, 0);
}

__device__ __forceinline__ unsigned short f2bf(float x) {
  union { float f; unsigned u; } a; a.f = x;
  unsigned r = a.u + 0x7FFFu + ((a.u >> 16) & 1u);
  return (unsigned short)(r >> 16);
}
__device__ __forceinline__ float bf2f(unsigned short b) {
  union { float f; unsigned u; } a; a.u = ((unsigned)b) << 16;
  return a.f;
}

// ---------------- prep: inputs -> A3 = [Ah | Ah | Al] (bf16, [4096][1536]) ----
__global__ __launch_bounds__(256) void prep_inputs(const float* __restrict__ x,
                                                   unsigned short* __restrict__ A3) {
  int idx = blockIdx.x * 256 + threadIdx.x;
  int n = idx >> 9, c = idx & 511;
  float v = x[idx];
  unsigned short hi = f2bf(v);
  unsigned short lo = f2bf(v - bf2f(hi));
  size_t base = (size_t)n * K3;
  A3[base + c] = hi;
  A3[base + 512 + c] = hi;
  A3[base + 1024 + c] = lo;
}

// ---------------- prep: weights -> B3T [512 c][1536 k] = [Wh;Wl;Wh]^T, PhT ----
__global__ __launch_bounds__(256) void prep_weights(const float* __restrict__ w,
                                                    const float* __restrict__ pw,
                                                    unsigned short* __restrict__ B3T,
                                                    unsigned short* __restrict__ PhT) {
  int idx = blockIdx.x * 256 + threadIdx.x;
  int c = idx >> 9, k = idx & 511;
  float v = w[(size_t)k * HD + c];
  unsigned short hi = f2bf(v);
  unsigned short lo = f2bf(v - bf2f(hi));
  size_t base = (size_t)c * K3;
  B3T[base + k] = hi;
  B3T[base + 512 + k] = lo;
  B3T[base + 1024 + k] = hi;
  float p = pw[(size_t)k * HD + c];
  PhT[(size_t)c * IND + k] = f2bf(p);
}

// ---------------- GEMM: 128x64 tiles, gll-staged dbuf, 1 barrier/iter --------
// z=0: support = A3 @ B3T^T (K=1536 split-bf16), writes support f32 + ST bf16^T
// z=1: resid   = Ah @ PhT^T (K=512) + projb + bias
__global__ __launch_bounds__(256) void gemm_kernel(
    const unsigned short* __restrict__ A3, const unsigned short* __restrict__ B3T,
    const unsigned short* __restrict__ PhT,
    float* __restrict__ support, unsigned short* __restrict__ ST,
    float* __restrict__ resid,
    const float* __restrict__ projb, const float* __restrict__ bias) {
  const int z = blockIdx.z;
  const unsigned short* Bp = z ? PhT : B3T;
  const int ldb = z ? IND : K3;
  const int K = z ? IND : K3;
  const int m0 = blockIdx.x * 128;
  const int n0 = blockIdx.y * 64;
  const int tid = threadIdx.x;
  const int lane = tid & 63;
  const int wv = tid >> 6;
  const int wm = wv & 1, wn = wv >> 1;

  __shared__ unsigned short As[2][128 * 32];
  __shared__ unsigned short Bs[2][64 * 32];

  f32x4 acc[4][2];
#pragma unroll
  for (int a = 0; a < 4; ++a)
#pragma unroll
    for (int b = 0; b < 2; ++b) acc[a][b] = (f32x4){0.f, 0.f, 0.f, 0.f};

  auto STAGE = [&](int buf, int k0) {
#pragma unroll
    for (int s = 0; s < 2; ++s) {
      int c = s * 256 + tid;
      int rr = c >> 2, ko = c & 3;
      gll16(A3 + (size_t)(m0 + rr) * K3 + k0 + ko * 8, &As[buf][c * 8]);
    }
    {
      int c = tid;
      int rr = c >> 2, ko = c & 3;
      gll16(Bp + (size_t)(n0 + rr) * ldb + k0 + ko * 8, &Bs[buf][c * 8]);
    }
  };

  STAGE(0, 0);
  __syncthreads();

  const int lrow = lane & 15;
  const int lkb = (lane >> 4) * 8;
  int buf = 0;
  for (int k0 = 0; k0 < K; k0 += 32) {
    if (k0 + 32 < K) STAGE(buf ^ 1, k0 + 32);
    bf16x8 af[4], bfr[2];
#pragma unroll
    for (int mf = 0; mf < 4; ++mf)
      af[mf] = *(const bf16x8*)(&As[buf][(wm * 64 + mf * 16 + lrow) * 32 + lkb]);
#pragma unroll
    for (int nf = 0; nf < 2; ++nf)
      bfr[nf] = *(const bf16x8*)(&Bs[buf][(wn * 32 + nf * 16 + lrow) * 32 + lkb]);
#pragma unroll
    for (int mf = 0; mf < 4; ++mf)
#pragma unroll
      for (int nf = 0; nf < 2; ++nf)
        acc[mf][nf] = __builtin_amdgcn_mfma_f32_16x16x32_bf16(af[mf], bfr[nf], acc[mf][nf], 0, 0, 0);
    __syncthreads();
    buf ^= 1;
  }

  const int lrow4 = (lane >> 4) * 4;
  const int lcol = lane & 15;
  if (z == 0) {
#pragma unroll
    for (int mf = 0; mf < 4; ++mf) {
#pragma unroll
      for (int nf = 0; nf < 2; ++nf) {
        int rg = m0 + wm * 64 + mf * 16 + lrow4;
        int cg = n0 + wn * 32 + nf * 16 + lcol;
#pragma unroll
        for (int q = 0; q < 4; ++q)
          support[(size_t)(rg + q) * HD + cg] = acc[mf][nf][q];
        us4 st4;
#pragma unroll
        for (int q = 0; q < 4; ++q) st4[q] = f2bf(acc[mf][nf][q]);
        *(us4*)(ST + (size_t)cg * NN + rg) = st4;
      }
    }
  } else {
#pragma unroll
    for (int mf = 0; mf < 4; ++mf) {
#pragma unroll
      for (int nf = 0; nf < 2; ++nf) {
        int rg = m0 + wm * 64 + mf * 16 + lrow4;
        int cg = n0 + wn * 32 + nf * 16 + lcol;
        float addv = projb[cg] + bias[cg];
#pragma unroll
        for (int q = 0; q < 4; ++q)
          resid[(size_t)(rg + q) * HD + cg] = acc[mf][nf][q] + addv;
      }
    }
  }
}

// ---------------- f1/f2 (scaled by log2 e) ----------------------------------
__global__ __launch_bounds__(256) void f1f2_kernel(const float* __restrict__ support,
                                                   const float* __restrict__ wu,
                                                   const float* __restrict__ wv,
                                                   float* __restrict__ g1,
                                                   float* __restrict__ g2) {
  int lane = threadIdx.x & 63;
  int n = blockIdx.x * 4 + (threadIdx.x >> 6);
  const float* srow = support + (size_t)n * HD + lane * 8;
  int h = lane >> 4;
  int d0 = (lane * 8) & 127;
  const float* u = wu + h * DH + d0;
  const float* v = wv + h * DH + d0;
  float du = 0.f, dv = 0.f;
#pragma unroll
  for (int e = 0; e < 8; ++e) {
    float s = srow[e];
    du += s * u[e];
    dv += s * v[e];
  }
#pragma unroll
  for (int off = 1; off < 16; off <<= 1) {
    du += __shfl_xor(du, off);
    dv += __shfl_xor(dv, off);
  }
  if ((lane & 15) == 0) {
    const float L2E = 1.4426950408889634f;
    g1[h * NN + n] = du * L2E;
    g2[h * NN + n] = dv * L2E;
  }
}

// ---------------- adjacency -> bitmask (pure ballot, HBM-bound) --------------
__global__ __launch_bounds__(256) void ballot_kernel(const float* __restrict__ adj,
                                                     unsigned long long* __restrict__ bm) {
  int i = blockIdx.x;
  int tid = threadIdx.x, lane = tid & 63, wv = tid >> 6;
  const float* arow = adj + (size_t)i * NN;
#pragma unroll 4
  for (int it = 0; it < 16; ++it) {
    int j = it * 256 + tid;
    unsigned long long b = __ballot(arow[j] != 0.0f);
    if (lane == 0) bm[(size_t)i * 64 + it * 4 + wv] = b;
  }
}

// ---------------- fused masked softmax + PV (partials, no max-sub) -----------
// grid (64 row-tiles, 4 heads, 2 j-chunks); 4 waves = 4 row-groups of 16.
__global__ __launch_bounds__(256) void attn_kernel(
    const unsigned short* __restrict__ ST,        // [512 d][4096 j] bf16
    const unsigned long long* __restrict__ bm,    // [4096 i][64 words]
    const float* __restrict__ g1, const float* __restrict__ g2,
    float* __restrict__ P, float* __restrict__ S) {
  const int bx = blockIdx.x;
  const int by = blockIdx.y;   // head
  const int bz = blockIdx.z;   // j-chunk (2048)
  const int tid = threadIdx.x;
  const int lane = tid & 63;
  const int w = tid >> 6;      // row-group

  __shared__ unsigned short tile[2][128 * 32];    // 16KB dbuf: [d][32 j]
  __shared__ unsigned long long bml[32 * 64];     // 16KB transposed: [word][row]
  __shared__ float g1l[2048];                     // 8KB

  // stage bitmask slice (transposed) + g1 slice
  {
    const unsigned long long* bsrc = bm + (size_t)bx * 64 * 64 + bz * 32;
#pragma unroll
    for (int s = 0; s < 8; ++s) {
      int idx = s * 256 + tid;               // 0..2047
      int r = idx >> 5, wi = idx & 31;
      bml[wi * 64 + r] = bsrc[(size_t)r * 64 + wi];
    }
    const float* gsrc = g1 + by * NN + bz * 2048;
#pragma unroll
    for (int s = 0; s < 2; ++s) {
      int idx = s * 256 + tid;
      *(f32x4*)(g1l + idx * 4) = *(const f32x4*)(gsrc + idx * 4);
    }
  }

  const int il = lane & 15;
  const int kg = lane >> 4;
  const int r = w * 16 + il;                 // local row 0..63
  const int ig = bx * 64 + r;
  const float g2v = g2[by * NN + ig];
  const float g2v5 = 0.2f * g2v;
  const unsigned short* stbase = ST + (size_t)by * 128 * NN + bz * 2048;

  auto STAGE = [&](int buf, int jt) {
#pragma unroll
    for (int s = 0; s < 2; ++s) {
      int c = s * 256 + tid;
      int d = c >> 2, jq = c & 3;
      gll16(stbase + (size_t)d * NN + jt + jq * 8, &tile[buf][c * 8]);
    }
  };

  STAGE(0, 0);
  __syncthreads();

  bf16x8 ones;
#pragma unroll
  for (int e = 0; e < 8; ++e) ones[e] = (short)0x3F80;

  f32x4 acc[8];
#pragma unroll
  for (int d = 0; d < 8; ++d) acc[d] = (f32x4){0.f, 0.f, 0.f, 0.f};
  f32x4 asum = (f32x4){0.f, 0.f, 0.f, 0.f};

  union F8 { f32x4 v[2]; float f[8]; };
  const char* bmlB = (const char*)bml;
  int buf = 0;

  for (int jt = 0; jt < 2048; jt += 32) {
    if (jt + 32 < 2048) STAGE(buf ^ 1, jt + 32);

    // mask byte: row r, bits [jt+kg*8, +8)
    int b = (jt >> 3) + kg;
    unsigned mby = (unsigned char)bmlB[((b >> 3) * 64 + r) * 8 + (b & 7)];

    F8 gc;
    gc.v[0] = *(const f32x4*)(g1l + jt + kg * 8);
    gc.v[1] = *(const f32x4*)(g1l + jt + kg * 8 + 4);

    bf16x8 bc[8];
#pragma unroll
    for (int d = 0; d < 8; ++d)
      bc[d] = *(const bf16x8*)(&tile[buf][(il + d * 16) * 32 + kg * 8]);

    float p[8];
#pragma unroll
    for (int e = 0; e < 8; ++e) {
      float a = gc.f[e] + g2v;                       // t*log2e
      float bb = __builtin_fmaf(0.2f, gc.f[e], g2v5); // 0.2*t*log2e
      float m = fmaxf(a, bb);                        // leaky-relu
      float pe = __builtin_amdgcn_exp2f(m);          // no max-sub (shift-invariant)
      int sext = -(int)((mby >> e) & 1u);            // 0 or -1
      union { float f; unsigned u; } pu; pu.f = pe;
      pu.u &= (unsigned)sext;                        // zero masked-out
      p[e] = pu.f;
    }

    union { unsigned u[4]; bf16x8 v; } af;
#pragma unroll
    for (int e2 = 0; e2 < 4; ++e2) {
      unsigned pk;
      asm("v_cvt_pk_bf16_f32 %0, %1, %2" : "=v"(pk) : "v"(p[2 * e2]), "v"(p[2 * e2 + 1]));
      af.u[e2] = pk;
    }

#pragma unroll
    for (int d = 0; d < 8; ++d)
      acc[d] = __builtin_amdgcn_mfma_f32_16x16x32_bf16(af.v, bc[d], acc[d], 0, 0, 0);
    asum = __builtin_amdgcn_mfma_f32_16x16x32_bf16(af.v, ones, asum, 0, 0, 0);

    __syncthreads();
    buf ^= 1;
  }

  // write partials
  float* Pp = P + (size_t)bz * NN * HD;
#pragma unroll
  for (int d = 0; d < 8; ++d) {
    int cg = by * 128 + d * 16 + il;
#pragma unroll
    for (int q = 0; q < 4; ++q) {
      int rg = bx * 64 + w * 16 + kg * 4 + q;
      Pp[(size_t)rg * HD + cg] = acc[d][q];
    }
  }
  if (il == 0) {
#pragma unroll
    for (int q = 0; q < 4; ++q) {
      int rg = bx * 64 + w * 16 + kg * 4 + q;
      S[((size_t)bz * 4 + by) * NN + rg] = asum[q];
    }
  }
}

// ---------------- merge partials + normalize + residual ----------------------
__global__ __launch_bounds__(256) void merge_kernel(const float* __restrict__ P,
                                                    const float* __restrict__ S,
                                                    const float* __restrict__ resid,
                                                    float* __restrict__ out) {
  int idx = blockIdx.x * 256 + threadIdx.x;   // 0..524287 (f32x4 groups)
  int i = idx >> 7;
  int c = (idx & 127) * 4;
  int h = c >> 7;
  f32x4 v0 = *(const f32x4*)(P + (size_t)i * HD + c);
  f32x4 v1 = *(const f32x4*)(P + (size_t)(NN + i) * HD + c);
  float s = S[(size_t)h * NN + i] + S[(size_t)(4 + h) * NN + i];
  float rs = s > 0.0f ? 1.0f / s : 0.0f;
  f32x4 rr = *(const f32x4*)(resid + (size_t)i * HD + c);
  f32x4 o;
#pragma unroll
  for (int q = 0; q < 4; ++q) o[q] = (v0[q] + v1[q]) * rs + rr[q];
  *(f32x4*)(out + (size_t)i * HD + c) = o;
}

// ---------------- launcher ---------------------------------------------------
extern "C" void kernel_launch(void* const* d_in, const int* in_sizes, int n_in,
                              void* d_out, int out_size, void* d_ws, size_t ws_size,
                              hipStream_t stream) {
  const float* inputs = (const float*)d_in[0];
  const float* adj = (const float*)d_in[1];
  const float* weight = (const float*)d_in[2];
  const float* wu = (const float*)d_in[3];
  const float* wv = (const float*)d_in[4];
  const float* bias = (const float*)d_in[5];
  const float* projw = (const float*)d_in[6];
  const float* projb = (const float*)d_in[7];
  float* out = (float*)d_out;

  char* ws = (char*)d_ws;
  size_t off = 0;
  unsigned short* A3 = (unsigned short*)(ws + off); off += (size_t)NN * K3 * 2;          // 12.58MB
  unsigned short* B3T = (unsigned short*)(ws + off); off += (size_t)HD * K3 * 2;         // 1.57MB
  unsigned short* PhT = (unsigned short*)(ws + off); off += (size_t)HD * IND * 2;        // 0.52MB
  float* support = (float*)(ws + off); off += (size_t)NN * HD * 4;                       // 8MB (ends 22.67MB)
  unsigned short* ST = (unsigned short*)(ws + off); off += (size_t)HD * NN * 2;          // 4MB
  float* resid = (float*)(ws + off); off += (size_t)NN * HD * 4;                         // 8MB
  float* g1 = (float*)(ws + off); off += (size_t)NH * NN * 4;
  float* g2 = (float*)(ws + off); off += (size_t)NH * NN * 4;
  unsigned long long* bm = (unsigned long long*)(ws + off); off += (size_t)NN * 64 * 8;  // 2MB

  // P/S OVERLAY dead buffers (A3/B3T/PhT/support are dead by the time attn runs):
  // P = ws+0 .. 16.78MB ; S = ws+17MB .. +128KB  (both < 22.67MB = end of support)
  float* P = (float*)(ws + 0);
  float* S = (float*)(ws + (size_t)17 * 1024 * 1024);

  prep_inputs<<<(NN * IND) / 256, 256, 0, stream>>>(inputs, A3);
  prep_weights<<<(IND * HD) / 256, 256, 0, stream>>>(weight, projw, B3T, PhT);
  gemm_kernel<<<dim3(32, 8, 2), 256, 0, stream>>>(A3, B3T, PhT, support, ST, resid, projb, bias);
  f1f2_kernel<<<NN / 4, 256, 0, stream>>>(support, wu, wv, g1, g2);
  ballot_kernel<<<NN, 256, 0, stream>>>(adj, bm);
  attn_kernel<<<dim3(64, 4, 2), 256, 0, stream>>>(ST, bm, g1, g2, P, S);
  merge_kernel<<<2048, 256, 0, stream>>>(P, S, resid, out);
}